// Round 6
// baseline (338.509 us; speedup 1.0000x reference)
//
#include <hip/hip_runtime.h>
#include <hip/hip_fp16.h>

#define NDIM 8192
#define KDIM 8192
#define NT 256          // N / 32 hash tiles
#define MOD2 4193281    // HASH_SIZE - 32*32 + 1
#define PRIME 2038074743LL

#define BM 128
#define BN 128
#define BK 32
#define KITER 64        // (KDIM/4)/BK, split-K = 4
#define ASTRIDE 40      // halves per A row (32 + 8 pad; 2-way bank alias = free)
#define BSLAB 1032      // halves per k-octet slab (128*8 + 4 pad dwords -> all 32 banks)

typedef _Float16 half8 __attribute__((ext_vector_type(8)));
typedef float floatx4 __attribute__((ext_vector_type(4)));

// ---------------- fused prepass: cvt fp32->f16, out=bias, ROBE-Z starts ----------------
__global__ __launch_bounds__(256) void prep_kernel(const float* __restrict__ x,
                                                   const float* __restrict__ hw,
                                                   const float* __restrict__ bias,
                                                   const int* __restrict__ rn,
                                                   __half* __restrict__ xh,
                                                   __half* __restrict__ hh,
                                                   int* __restrict__ starts,
                                                   float* __restrict__ out) {
    int b = blockIdx.x;
    int tid = threadIdx.x;
    if (b < 8192) {                       // cvt: 2M threads x 4 floats
        int i = b * 256 + tid;
        const float4* s; __half2* d; int j;
        if (i < (1 << 20)) { s = (const float4*)x;  d = (__half2*)xh; j = i; }
        else               { s = (const float4*)hw; d = (__half2*)hh; j = i - (1 << 20); }
        float4 v = s[j];
        d[j * 2]     = __floats2half2_rn(v.x, v.y);
        d[j * 2 + 1] = __floats2half2_rn(v.z, v.w);
    } else if (b < 8192 + 4096) {         // init: out = bias (atomic targets)
        int i = (b - 8192) * 256 + tid;
        float4 bv = *(const float4*)(bias + ((i & 2047) << 2));
        ((float4*)out)[i] = bv;
    } else {                              // starts: 64K hash tile offsets
        int t = (b - 12288) * 256 + tid;
        bool is64 = (rn[1] == 0 && rn[3] == 0);   // int64 input: words 1,3 are hi-halves
        long long R1 = is64 ? rn[2] : rn[1];
        long long R2 = is64 ? rn[4] : rn[2];
        long long R3 = is64 ? rn[6] : rn[3];
        long long k_id = t >> 8, n_id = t & 255;
        long long v = (k_id * R3 + n_id * R2 + R1) % PRIME;
        starts[t] = (int)(v % MOD2);
    }
}

// ---------------- main GEMM: split-K=4, 128x128 block, 4 waves, dist-2 prefetch ----------------
__global__ __launch_bounds__(256, 3) void gemm_kernel(
    const __half* __restrict__ xh, const __half* __restrict__ hh,
    const int* __restrict__ starts, float* __restrict__ out) {
    __shared__ __align__(16) __half As[2][BM * ASTRIDE];   // [m][k] padded
    __shared__ __align__(16) __half Bs[2][4 * BSLAB];      // [k-octet][n][8] k-runs
    __shared__ int Ss[KITER * 4];                          // per-block starts table

    const int tid = threadIdx.x;
    const int lane = tid & 63;
    const int wave = tid >> 6;       // 0..3
    const int wm = wave >> 1;        // 0..1 : 64-row strip
    const int wn = wave & 1;         // 0..1 : 64-col strip
    const int quad = lane >> 4;
    const int l16 = lane & 15;

    // block decode: XCD (= i%8) keeps (ks, m_blk&1) fixed -> A panels L2-local
    const int i = blockIdx.x;        // 1024 blocks
    const int ks = i & 3;
    const int m_blk = (i >> 2) & 3;
    const int n_blk = i >> 4;        // 0..63
    const int gm0 = m_blk * BM;
    const int gn0 = n_blk * BN;
    const int kt0 = ks * KITER;
    const int n_id0 = n_blk * 4;

    Ss[tid] = starts[(kt0 + (tid >> 2)) * NT + n_id0 + (tid & 3)];  // 256 = KITER*4

    // A staging: 2 threads per row, 32 B each (contiguous)
    const int a_row = tid >> 1;               // 0..127
    const int a_ch = tid & 1;
    const __half* aptr = xh + (size_t)(gm0 + a_row) * KDIM + kt0 * 32 + a_ch * 16;
    const unsigned a_woff = a_row * ASTRIDE + a_ch * 16;

    // B staging: wave stages hash tile `wave`; lane covers one k-run pair
    const int b_np = lane & 15;               // n-pair
    const int b_kg = lane >> 4;               // k-octet 0..3
    const unsigned b_woff = b_kg * BSLAB + (wave * 32 + 2 * b_np) * 8;

    uint4 pa[2][2];
    unsigned pb[2][8];

#define LOADT(s_, kp_) do {                                                    \
        pa[s_][0] = *(const uint4*)(aptr + (kp_) * 32);                        \
        pa[s_][1] = *(const uint4*)(aptr + (kp_) * 32 + 8);                    \
        int st = Ss[(kp_) * 4 + wave];                                         \
        const __half* src = hh + st + b_kg * 256 + b_np * 2;                   \
        pb[s_][0] = *(const unsigned*)(src);                                   \
        pb[s_][1] = *(const unsigned*)(src + 32);                              \
        pb[s_][2] = *(const unsigned*)(src + 64);                              \
        pb[s_][3] = *(const unsigned*)(src + 96);                              \
        pb[s_][4] = *(const unsigned*)(src + 128);                             \
        pb[s_][5] = *(const unsigned*)(src + 160);                             \
        pb[s_][6] = *(const unsigned*)(src + 192);                             \
        pb[s_][7] = *(const unsigned*)(src + 224);                             \
    } while (0)

#define STORET(s_, buf_) do {                                                  \
        *(uint4*)&As[buf_][a_woff] = pa[s_][0];                                \
        *(uint4*)&As[buf_][a_woff + 8] = pa[s_][1];                            \
        unsigned e0 = (pb[s_][0] & 0xffffu) | (pb[s_][1] << 16);               \
        unsigned e1 = (pb[s_][2] & 0xffffu) | (pb[s_][3] << 16);               \
        unsigned e2 = (pb[s_][4] & 0xffffu) | (pb[s_][5] << 16);               \
        unsigned e3 = (pb[s_][6] & 0xffffu) | (pb[s_][7] << 16);               \
        unsigned o0 = (pb[s_][0] >> 16) | (pb[s_][1] & 0xffff0000u);           \
        unsigned o1 = (pb[s_][2] >> 16) | (pb[s_][3] & 0xffff0000u);           \
        unsigned o2 = (pb[s_][4] >> 16) | (pb[s_][5] & 0xffff0000u);           \
        unsigned o3 = (pb[s_][6] >> 16) | (pb[s_][7] & 0xffff0000u);           \
        *(uint4*)&Bs[buf_][b_woff] = (uint4){e0, e1, e2, e3};                  \
        *(uint4*)&Bs[buf_][b_woff + 8] = (uint4){o0, o1, o2, o3};              \
    } while (0)

    floatx4 acc[4][4];
#pragma unroll
    for (int r = 0; r < 4; r++)
#pragma unroll
        for (int c = 0; c < 4; c++)
            acc[r][c] = (floatx4){0.f, 0.f, 0.f, 0.f};

    __syncthreads();                  // Ss visible
    LOADT(0, 0);
    LOADT(1, 1);
    STORET(0, 0);                     // vmcnt waits set0 only; set1 stays in flight
    __syncthreads();

    for (int kp = 0; kp < KITER; kp++) {
        const int cur = kp & 1;
        if (kp + 2 < KITER) LOADT(cur, kp + 2);   // set cur freed by last iter's STORET

        half8 af[4], bf[4];
#pragma unroll
        for (int r = 0; r < 4; r++)
            af[r] = *(const half8*)&As[cur][(wm * 64 + r * 16 + l16) * ASTRIDE + quad * 8];
#pragma unroll
        for (int c = 0; c < 4; c++)
            bf[c] = *(const half8*)&Bs[cur][quad * BSLAB + (wn * 64 + c * 16 + l16) * 8];

#pragma unroll
        for (int r = 0; r < 4; r++)
#pragma unroll
            for (int c = 0; c < 4; c++)
                acc[r][c] = __builtin_amdgcn_mfma_f32_16x16x32_f16(af[r], bf[c], acc[r][c], 0, 0, 0);

        if (kp + 1 < KITER) STORET((kp + 1) & 1, (kp + 1) & 1);  // tile kp+1, loaded last iter
        __syncthreads();
    }

    // ---- epilogue: atomic accumulate (C/D layout col=lane&15, row=quad*4+reg) ----
#pragma unroll
    for (int c = 0; c < 4; c++) {
        int col = gn0 + wn * 64 + c * 16 + l16;
#pragma unroll
        for (int r = 0; r < 4; r++) {
            int row0 = gm0 + wm * 64 + r * 16 + quad * 4;
#pragma unroll
            for (int e = 0; e < 4; e++)
                atomicAdd(&out[(size_t)(row0 + e) * NDIM + col], acc[r][c][e]);
        }
    }
#undef LOADT
#undef STORET
}

extern "C" void kernel_launch(void* const* d_in, const int* in_sizes, int n_in,
                              void* d_out, int out_size, void* d_ws, size_t ws_size,
                              hipStream_t stream) {
    const float* x = (const float*)d_in[0];
    const float* hw = (const float*)d_in[1];
    const float* bias = (const float*)d_in[2];
    const int* rn = (const int*)d_in[3];
    float* out = (float*)d_out;

    char* ws = (char*)d_ws;
    __half* xh = (__half*)ws;                          // 8 MB : x as f16
    __half* hh = (__half*)(ws + (8u << 20));           // 8 MB : hashed_weight as f16
    int* starts = (int*)(ws + (16u << 20));            // 256 KB : tile start table

    hipLaunchKernelGGL(prep_kernel, dim3(12544), dim3(256), 0, stream,
                       x, hw, bias, rn, xh, hh, starts, out);
    hipLaunchKernelGGL(gemm_kernel, dim3(1024), dim3(256), 0, stream, xh, hh, starts, out);
}

// Round 7
// 305.083 us; speedup vs baseline: 1.1096x; 1.1096x over previous
//
#include <hip/hip_runtime.h>
#include <hip/hip_fp16.h>

#define NDIM 8192
#define KDIM 8192
#define NT 256          // N / 32 hash tiles
#define MOD2 4193281    // HASH_SIZE - 32*32 + 1
#define PRIME 2038074743LL

#define BM 256
#define BN 128
#define BK 32
#define KITER 64        // (KDIM/4)/BK, split-K = 4
#define ASTRIDE 40      // halves per A row (32 + 8 pad; 2-way bank alias = free)
#define BSLAB 1032      // halves per k-octet slab (128*8 + 4 pad dwords -> all 32 banks)

typedef _Float16 half8 __attribute__((ext_vector_type(8)));
typedef float floatx4 __attribute__((ext_vector_type(4)));

// ---------------- fused prepass: cvt fp32->f16, out=bias, ROBE-Z starts ----------------
__global__ __launch_bounds__(256) void prep_kernel(const float* __restrict__ x,
                                                   const float* __restrict__ hw,
                                                   const float* __restrict__ bias,
                                                   const int* __restrict__ rn,
                                                   __half* __restrict__ xh,
                                                   __half* __restrict__ hh,
                                                   int* __restrict__ starts,
                                                   float* __restrict__ out) {
    int b = blockIdx.x;
    int tid = threadIdx.x;
    if (b < 8192) {                       // cvt: 2M threads x 4 floats
        int i = b * 256 + tid;
        const float4* s; __half2* d; int j;
        if (i < (1 << 20)) { s = (const float4*)x;  d = (__half2*)xh; j = i; }
        else               { s = (const float4*)hw; d = (__half2*)hh; j = i - (1 << 20); }
        float4 v = s[j];
        d[j * 2]     = __floats2half2_rn(v.x, v.y);
        d[j * 2 + 1] = __floats2half2_rn(v.z, v.w);
    } else if (b < 8192 + 4096) {         // init: out = bias (atomic targets)
        int i = (b - 8192) * 256 + tid;
        float4 bv = *(const float4*)(bias + ((i & 2047) << 2));
        ((float4*)out)[i] = bv;
    } else {                              // starts: 64K hash tile offsets
        int t = (b - 12288) * 256 + tid;
        bool is64 = (rn[1] == 0 && rn[3] == 0);   // int64 input: words 1,3 are hi-halves
        long long R1 = is64 ? rn[2] : rn[1];
        long long R2 = is64 ? rn[4] : rn[2];
        long long R3 = is64 ? rn[6] : rn[3];
        long long k_id = t >> 8, n_id = t & 255;
        long long v = (k_id * R3 + n_id * R2 + R1) % PRIME;
        starts[t] = (int)(v % MOD2);
    }
}

// ---------------- main GEMM: split-K=4, 256x128 block, dist-2 prefetch ----------------
__global__ __launch_bounds__(512, 4) void gemm_kernel(
    const __half* __restrict__ xh, const __half* __restrict__ hh,
    const int* __restrict__ starts, float* __restrict__ out) {
    __shared__ __align__(16) __half As[2][BM * ASTRIDE];   // [m][k] padded
    __shared__ __align__(16) __half Bs[2][4 * BSLAB];      // [k-octet][n][8] k-runs
    __shared__ int Ss[KITER * 4];                          // per-block starts table

    const int tid = threadIdx.x;
    const int lane = tid & 63;
    const int wave = tid >> 6;       // 0..7
    const int wm = wave >> 1;        // 0..3 : 64-row strip
    const int wn = wave & 1;         // 0..1 : 64-col strip
    const int quad = lane >> 4;
    const int l16 = lane & 15;

    // block decode: ks = i>>7 (128 = 0 mod 8) -> all 4 split-K copies of an
    // output tile land on the SAME XCD; atomic lines stay in one L2.
    const int i = blockIdx.x;        // 512 blocks
    const int ks = i >> 7;           // 0..3
    const int m_blk = i & 1;
    const int n_blk = (i >> 1) & 63;
    const int gm0 = m_blk * BM;
    const int gn0 = n_blk * BN;
    const int kt0 = ks * KITER;
    const int n_id0 = n_blk * 4;     // 4 hash tiles per block

    if (tid < KITER * 4) {
        int kp = tid >> 2, tile = tid & 3;
        Ss[tid] = starts[(kt0 + kp) * NT + n_id0 + tile];
    }

    // A staging: thread covers rows (tid>>2) and (tid>>2)+128, 16B chunk tid&3
    const int a_row = tid >> 2;               // 0..127
    const int a_ch = tid & 3;
    const __half* aptr = xh + (size_t)(gm0 + a_row) * KDIM + kt0 * 32 + a_ch * 8;
    const unsigned a_woff = a_row * ASTRIDE + a_ch * 8;

    // B staging: thread covers 2 n x 4 k of one 32x32 hash tile
    const int b_tile = tid >> 7;              // 0..3
    const int t7 = tid & 127;
    const int b_np = t7 & 15;                 // n-pair
    const int b_kg = t7 >> 4;                 // 0..7 : 4-k group
    const int b_oct = b_kg >> 1;
    const unsigned b_woff = b_oct * BSLAB + (b_tile * 32 + 2 * b_np) * 8 + (b_kg & 1) * 4;

    uint4 pa[2][2];
    unsigned pb[2][4];

#define LOADT(s_, kp_) do {                                                    \
        pa[s_][0] = *(const uint4*)(aptr + (kp_) * 32);                        \
        pa[s_][1] = *(const uint4*)(aptr + (size_t)128 * KDIM + (kp_) * 32);   \
        int st = Ss[(kp_) * 4 + b_tile];                                       \
        const __half* src = hh + st + b_kg * 128 + b_np * 2;                   \
        pb[s_][0] = *(const unsigned*)(src);                                   \
        pb[s_][1] = *(const unsigned*)(src + 32);                              \
        pb[s_][2] = *(const unsigned*)(src + 64);                              \
        pb[s_][3] = *(const unsigned*)(src + 96);                              \
    } while (0)

#define STORET(s_, buf_) do {                                                  \
        *(uint4*)&As[buf_][a_woff] = pa[s_][0];                                \
        *(uint4*)&As[buf_][(a_woff) + 128 * ASTRIDE] = pa[s_][1];              \
        unsigned lo0 = (pb[s_][0] & 0xffffu) | (pb[s_][1] << 16);              \
        unsigned lo1 = (pb[s_][2] & 0xffffu) | (pb[s_][3] << 16);              \
        unsigned hi0 = (pb[s_][0] >> 16) | (pb[s_][1] & 0xffff0000u);          \
        unsigned hi1 = (pb[s_][2] >> 16) | (pb[s_][3] & 0xffff0000u);          \
        uint2 e = {lo0, lo1}, o = {hi0, hi1};                                  \
        *(uint2*)&Bs[buf_][b_woff] = e;                                        \
        *(uint2*)&Bs[buf_][b_woff + 8] = o;                                    \
    } while (0)

    floatx4 acc[4][4];
#pragma unroll
    for (int r = 0; r < 4; r++)
#pragma unroll
        for (int c = 0; c < 4; c++)
            acc[r][c] = (floatx4){0.f, 0.f, 0.f, 0.f};

    __syncthreads();                  // Ss visible
    LOADT(0, 0);
    LOADT(1, 1);
    STORET(0, 0);                     // waits set0 only; set1 stays in flight
    __syncthreads();

    for (int kp = 0; kp < KITER; kp++) {
        const int cur = kp & 1;
        if (kp + 2 < KITER) LOADT(cur, kp + 2);   // reg set `cur` was freed last iter

        half8 af[4], bf[4];
#pragma unroll
        for (int r = 0; r < 4; r++)
            af[r] = *(const half8*)&As[cur][(wm * 64 + r * 16 + l16) * ASTRIDE + quad * 8];
#pragma unroll
        for (int c = 0; c < 4; c++)
            bf[c] = *(const half8*)&Bs[cur][quad * BSLAB + (wn * 64 + c * 16 + l16) * 8];

#pragma unroll
        for (int r = 0; r < 4; r++)
#pragma unroll
            for (int c = 0; c < 4; c++)
                acc[r][c] = __builtin_amdgcn_mfma_f32_16x16x32_f16(af[r], bf[c], acc[r][c], 0, 0, 0);

        if (kp + 1 < KITER) STORET((kp + 1) & 1, (kp + 1) & 1);  // loads from iter kp-1
        __syncthreads();
    }

    // ---- epilogue: atomic accumulate (C/D layout col=lane&15, row=quad*4+reg) ----
#pragma unroll
    for (int c = 0; c < 4; c++) {
        int col = gn0 + wn * 64 + c * 16 + l16;
#pragma unroll
        for (int r = 0; r < 4; r++) {
            int row0 = gm0 + wm * 64 + r * 16 + quad * 4;
#pragma unroll
            for (int e = 0; e < 4; e++)
                atomicAdd(&out[(size_t)(row0 + e) * NDIM + col], acc[r][c][e]);
        }
    }
#undef LOADT
#undef STORET
}

extern "C" void kernel_launch(void* const* d_in, const int* in_sizes, int n_in,
                              void* d_out, int out_size, void* d_ws, size_t ws_size,
                              hipStream_t stream) {
    const float* x = (const float*)d_in[0];
    const float* hw = (const float*)d_in[1];
    const float* bias = (const float*)d_in[2];
    const int* rn = (const int*)d_in[3];
    float* out = (float*)d_out;

    char* ws = (char*)d_ws;
    __half* xh = (__half*)ws;                          // 8 MB : x as f16
    __half* hh = (__half*)(ws + (8u << 20));           // 8 MB : hashed_weight as f16
    int* starts = (int*)(ws + (16u << 20));            // 256 KB : tile start table

    hipLaunchKernelGGL(prep_kernel, dim3(12544), dim3(256), 0, stream,
                       x, hw, bias, rn, xh, hh, starts, out);
    hipLaunchKernelGGL(gemm_kernel, dim3(512), dim3(512), 0, stream, xh, hh, starts, out);
}

// Round 8
// 201.090 us; speedup vs baseline: 1.6834x; 1.5171x over previous
//
#include <hip/hip_runtime.h>
#include <hip/hip_fp16.h>

#define NDIM 8192
#define KDIM 8192
#define NT 256          // N / 32 hash tiles
#define MOD2 4193281    // HASH_SIZE - 32*32 + 1
#define PRIME 2038074743LL

#define BM 256
#define BN 128
#define BK 32
#define KITER 64        // (KDIM/4)/BK, split-K = 4
#define ASTRIDE 40      // halves per A row (32 + 8 pad; b128-aligned, phase-balanced)
#define BSLAB 1032      // halves per k-octet slab (128*8 + 8 pad; phase-balanced)

typedef _Float16 half8 __attribute__((ext_vector_type(8)));
typedef float floatx4 __attribute__((ext_vector_type(4)));

// ---------------- fused prepass: cvt fp32->f16, out=bias, ROBE-Z starts ----------------
__global__ __launch_bounds__(256) void prep_kernel(const float* __restrict__ x,
                                                   const float* __restrict__ hw,
                                                   const float* __restrict__ bias,
                                                   const int* __restrict__ rn,
                                                   __half* __restrict__ xh,
                                                   __half* __restrict__ hh,
                                                   int* __restrict__ starts,
                                                   float* __restrict__ out) {
    int b = blockIdx.x;
    int tid = threadIdx.x;
    if (b < 8192) {                       // cvt: 2M threads x 4 floats
        int i = b * 256 + tid;
        const float4* s; __half2* d; int j;
        if (i < (1 << 20)) { s = (const float4*)x;  d = (__half2*)xh; j = i; }
        else               { s = (const float4*)hw; d = (__half2*)hh; j = i - (1 << 20); }
        float4 v = s[j];
        d[j * 2]     = __floats2half2_rn(v.x, v.y);
        d[j * 2 + 1] = __floats2half2_rn(v.z, v.w);
    } else if (b < 8192 + 4096) {         // init: out = bias (atomic targets)
        int i = (b - 8192) * 256 + tid;
        float4 bv = *(const float4*)(bias + ((i & 2047) << 2));
        ((float4*)out)[i] = bv;
    } else {                              // starts: 64K hash tile offsets
        int t = (b - 12288) * 256 + tid;
        bool is64 = (rn[1] == 0 && rn[3] == 0);   // int64 input: words 1,3 are hi-halves
        long long R1 = is64 ? rn[2] : rn[1];
        long long R2 = is64 ? rn[4] : rn[2];
        long long R3 = is64 ? rn[6] : rn[3];
        long long k_id = t >> 8, n_id = t & 255;
        long long v = (k_id * R3 + n_id * R2 + R1) % PRIME;
        starts[t] = (int)(v % MOD2);
    }
}

// ---------------- main GEMM: split-K=4, 256x128 block, manual dist-2 prefetch ----------------
__global__ __launch_bounds__(512, 4) void gemm_kernel(
    const __half* __restrict__ xh, const __half* __restrict__ hh,
    const int* __restrict__ starts, float* __restrict__ out) {
    __shared__ __align__(16) __half As[2][BM * ASTRIDE];   // [m][k] padded
    __shared__ __align__(16) __half Bs[2][4 * BSLAB];      // [k-octet][n][8] k-runs
    __shared__ int Ss[KITER * 4];                          // per-block starts table

    const int tid = threadIdx.x;
    const int lane = tid & 63;
    const int wave = tid >> 6;       // 0..7
    const int wm = wave >> 1;        // 0..3 : 64-row strip
    const int wn = wave & 1;         // 0..1 : 64-col strip
    const int quad = lane >> 4;
    const int l16 = lane & 15;

    // block decode: R5-verbatim (proven 64 MB atomic write, 129 us)
    const int i = blockIdx.x;        // 512 blocks
    const int ks = i & 3;
    const int m_blk = (i >> 2) & 1;
    const int n_blk = i >> 3;        // 0..63
    const int gm0 = m_blk * BM;
    const int gn0 = n_blk * BN;
    const int kt0 = ks * KITER;
    const int n_id0 = n_blk * 4;     // 4 hash tiles per block

    if (tid < KITER * 4) {
        int kp = tid >> 2, tile = tid & 3;
        Ss[tid] = starts[(kt0 + kp) * NT + n_id0 + tile];
    }

    // A staging: thread covers rows (tid>>2) and (tid>>2)+128, 16B chunk tid&3
    const int a_row = tid >> 2;               // 0..127
    const int a_ch = tid & 3;
    const __half* aptr = xh + (size_t)(gm0 + a_row) * KDIM + kt0 * 32 + a_ch * 8;
    const unsigned a_woff = a_row * ASTRIDE + a_ch * 8;

    // B staging: thread covers 2 n x 4 k of one 32x32 hash tile
    const int b_tile = tid >> 7;              // 0..3
    const int t7 = tid & 127;
    const int b_np = t7 & 15;                 // n-pair
    const int b_kg = t7 >> 4;                 // 0..7 : 4-k group
    const int b_oct = b_kg >> 1;
    const unsigned b_woff = b_oct * BSLAB + (b_tile * 32 + 2 * b_np) * 8 + (b_kg & 1) * 4;

    // two STATIC register sets (no arrays -> no dynamic indexing -> no spill)
    uint4 paA0, paA1, paB0, paB1;
    unsigned pbA0, pbA1, pbA2, pbA3, pbB0, pbB1, pbB2, pbB3;

#define LOADT(P0, P1, Q0, Q1, Q2, Q3, kp_) do {                                \
        P0 = *(const uint4*)(aptr + (kp_) * 32);                               \
        P1 = *(const uint4*)(aptr + (size_t)128 * KDIM + (kp_) * 32);          \
        int st = Ss[(kp_) * 4 + b_tile];                                       \
        const __half* src = hh + st + b_kg * 128 + b_np * 2;                   \
        Q0 = *(const unsigned*)(src);                                          \
        Q1 = *(const unsigned*)(src + 32);                                     \
        Q2 = *(const unsigned*)(src + 64);                                     \
        Q3 = *(const unsigned*)(src + 96);                                     \
    } while (0)

#define STORET(P0, P1, Q0, Q1, Q2, Q3, buf_) do {                              \
        *(uint4*)&As[buf_][a_woff] = P0;                                       \
        *(uint4*)&As[buf_][(a_woff) + 128 * ASTRIDE] = P1;                     \
        unsigned lo0 = (Q0 & 0xffffu) | (Q1 << 16);                            \
        unsigned lo1 = (Q2 & 0xffffu) | (Q3 << 16);                            \
        unsigned hi0 = (Q0 >> 16) | (Q1 & 0xffff0000u);                        \
        unsigned hi1 = (Q2 >> 16) | (Q3 & 0xffff0000u);                        \
        uint2 e = {lo0, lo1}, o = {hi0, hi1};                                  \
        *(uint2*)&Bs[buf_][b_woff] = e;                                        \
        *(uint2*)&Bs[buf_][b_woff + 8] = o;                                    \
    } while (0)

    floatx4 acc[4][4];
#pragma unroll
    for (int r = 0; r < 4; r++)
#pragma unroll
        for (int c = 0; c < 4; c++)
            acc[r][c] = (floatx4){0.f, 0.f, 0.f, 0.f};

#define FRAGS_MFMA(buf_) do {                                                  \
        half8 af[4], bf[4];                                                    \
        _Pragma("unroll")                                                      \
        for (int r = 0; r < 4; r++)                                            \
            af[r] = *(const half8*)&As[buf_][(wm * 64 + r * 16 + l16) * ASTRIDE + quad * 8]; \
        _Pragma("unroll")                                                      \
        for (int c = 0; c < 4; c++)                                            \
            bf[c] = *(const half8*)&Bs[buf_][quad * BSLAB + (wn * 64 + c * 16 + l16) * 8];   \
        _Pragma("unroll")                                                      \
        for (int r = 0; r < 4; r++)                                            \
            _Pragma("unroll")                                                  \
            for (int c = 0; c < 4; c++)                                        \
                acc[r][c] = __builtin_amdgcn_mfma_f32_16x16x32_f16(af[r], bf[c], acc[r][c], 0, 0, 0); \
    } while (0)

    __syncthreads();                  // Ss visible
    LOADT(paA0, paA1, pbA0, pbA1, pbA2, pbA3, 0);   // tile 0 -> set A
    LOADT(paB0, paB1, pbB0, pbB1, pbB2, pbB3, 1);   // tile 1 -> set B
    STORET(paA0, paA1, pbA0, pbA1, pbA2, pbA3, 0);  // waits set A only
    __syncthreads();

    for (int kp = 0; kp < KITER; kp += 2) {
        // even half-iter: compute tile kp from buf0; set A free
        if (kp + 2 < KITER) LOADT(paA0, paA1, pbA0, pbA1, pbA2, pbA3, kp + 2);
        FRAGS_MFMA(0);
        STORET(paB0, paB1, pbB0, pbB1, pbB2, pbB3, 1);   // tile kp+1 (loaded 1 iter ago)
        __syncthreads();

        // odd half-iter: compute tile kp+1 from buf1; set B free
        if (kp + 3 < KITER) LOADT(paB0, paB1, pbB0, pbB1, pbB2, pbB3, kp + 3);
        FRAGS_MFMA(1);
        if (kp + 2 < KITER)
            STORET(paA0, paA1, pbA0, pbA1, pbA2, pbA3, 0); // tile kp+2 (loaded 1 iter ago)
        __syncthreads();
    }

    // ---- epilogue: atomic accumulate (C/D layout col=lane&15, row=quad*4+reg) ----
#pragma unroll
    for (int c = 0; c < 4; c++) {
        int col = gn0 + wn * 64 + c * 16 + l16;
#pragma unroll
        for (int r = 0; r < 4; r++) {
            int row0 = gm0 + wm * 64 + r * 16 + quad * 4;
#pragma unroll
            for (int e = 0; e < 4; e++)
                atomicAdd(&out[(size_t)(row0 + e) * NDIM + col], acc[r][c][e]);
        }
    }
#undef LOADT
#undef STORET
#undef FRAGS_MFMA
}

extern "C" void kernel_launch(void* const* d_in, const int* in_sizes, int n_in,
                              void* d_out, int out_size, void* d_ws, size_t ws_size,
                              hipStream_t stream) {
    const float* x = (const float*)d_in[0];
    const float* hw = (const float*)d_in[1];
    const float* bias = (const float*)d_in[2];
    const int* rn = (const int*)d_in[3];
    float* out = (float*)d_out;

    char* ws = (char*)d_ws;
    __half* xh = (__half*)ws;                          // 8 MB : x as f16
    __half* hh = (__half*)(ws + (8u << 20));           // 8 MB : hashed_weight as f16
    int* starts = (int*)(ws + (16u << 20));            // 256 KB : tile start table

    hipLaunchKernelGGL(prep_kernel, dim3(12544), dim3(256), 0, stream,
                       x, hw, bias, rn, xh, hh, starts, out);
    hipLaunchKernelGGL(gemm_kernel, dim3(512), dim3(512), 0, stream, xh, hh, starts, out);
}